// Round 13
// baseline (275.019 us; speedup 1.0000x reference)
//
#include <hip/hip_runtime.h>
#include <math.h>

#define BDIM 2
#define TT 1024
#define NH 8
#define HD 64
#define NTOPK 16
#define NBH 16     // BDIM*NH
#define NTOK 16384 // NBH*TT

// ---------------------------------------------------------------------------
// Collapse the linear-linear pair MLPs into 128-dim fp64 vectors.
// ---------------------------------------------------------------------------
__global__ __launch_bounds__(256) void k_collapse64(
    const float* __restrict__ Wpi, const float* __restrict__ bpi,
    const float* __restrict__ Wpo, const float* __restrict__ bpo,
    const float* __restrict__ Wti, const float* __restrict__ bti,
    const float* __restrict__ Wto, const float* __restrict__ bto,
    double* __restrict__ wphid, double* __restrict__ wtaud,
    double* __restrict__ ccd) {
  int tid = threadIdx.x;
  int blk = blockIdx.x;
  if (blk < 16) {
    int r = blk * 16 + (tid >> 4);
    int l = tid & 15;
    double s = 0.;
    if (r < 128) {
      for (int i = 0; i < 32; ++i)
        s += (double)Wpi[r * 512 + l + 16 * i] * (double)Wpo[l + 16 * i];
    } else {
      int rr = r - 128;
      for (int i = 0; i < 16; ++i)
        s += (double)Wti[rr * 256 + l + 16 * i] * (double)Wto[l + 16 * i];
    }
#pragma unroll
    for (int off = 8; off >= 1; off >>= 1) s += __shfl_xor(s, off, 64);
    if (l == 0) {
      if (r < 128) wphid[r] = s;
      else wtaud[r - 128] = s;
    }
  } else {
    int lane = tid & 63;
    if (tid < 64) {
      double p = 0.;
      for (int c = lane; c < 512; c += 64) p += (double)bpi[c] * (double)Wpo[c];
#pragma unroll
      for (int off = 32; off >= 1; off >>= 1) p += __shfl_xor(p, off, 64);
      if (lane == 0) ccd[0] = p + (double)bpo[0];
    } else if (tid < 128) {
      double p = 0.;
      for (int c = lane; c < 256; c += 64) p += (double)bti[c] * (double)Wto[c];
#pragma unroll
      for (int off = 32; off >= 1; off >>= 1) p += __shfl_xor(p, off, 64);
      if (lane == 0) ccd[1] = p + (double)bto[0];
    }
  }
}

// ---------------------------------------------------------------------------
// fp32 GEMM 64x64 tile, BK=64, strict sequential-k fmaf per output element
// (BLAS-order rounding — required for reference-matching top-k selection).
// ---------------------------------------------------------------------------
__device__ __forceinline__ void gemm_body(
    const float* __restrict__ A, const float* __restrict__ W,
    const float* __restrict__ bias, float* __restrict__ out,
    int bm, int bn, int mode) {
  __shared__ float As[64][68];
  __shared__ float Bs[64][64];
  const int tid = threadIdx.x;
  const int tx = tid & 15;
  const int ty = tid >> 4;
  float acc[4][4] = {{0.f, 0.f, 0.f, 0.f}};
  for (int k0 = 0; k0 < 512; k0 += 64) {
#pragma unroll
    for (int i = 0; i < 4; ++i) {
      int idx = i * 256 + tid;
      int row = idx >> 4;
      int c4 = (idx & 15) << 2;
      float4 av = *(const float4*)&A[(bm + row) * 512 + k0 + c4];
      As[c4 + 0][row] = av.x;
      As[c4 + 1][row] = av.y;
      As[c4 + 2][row] = av.z;
      As[c4 + 3][row] = av.w;
    }
#pragma unroll
    for (int i = 0; i < 4; ++i) {
      int idx = i * 256 + tid;
      int br = idx >> 4;
      int bc = (idx & 15) << 2;
      *(float4*)&Bs[br][bc] = *(const float4*)&W[(k0 + br) * 512 + bn + bc];
    }
    __syncthreads();
#pragma unroll
    for (int kk = 0; kk < 64; ++kk) {
      float4 a = *(const float4*)&As[kk][ty * 4];
      float4 b = *(const float4*)&Bs[kk][tx << 2];
      acc[0][0] = fmaf(a.x, b.x, acc[0][0]);
      acc[0][1] = fmaf(a.x, b.y, acc[0][1]);
      acc[0][2] = fmaf(a.x, b.z, acc[0][2]);
      acc[0][3] = fmaf(a.x, b.w, acc[0][3]);
      acc[1][0] = fmaf(a.y, b.x, acc[1][0]);
      acc[1][1] = fmaf(a.y, b.y, acc[1][1]);
      acc[1][2] = fmaf(a.y, b.z, acc[1][2]);
      acc[1][3] = fmaf(a.y, b.w, acc[1][3]);
      acc[2][0] = fmaf(a.z, b.x, acc[2][0]);
      acc[2][1] = fmaf(a.z, b.y, acc[2][1]);
      acc[2][2] = fmaf(a.z, b.z, acc[2][2]);
      acc[2][3] = fmaf(a.z, b.w, acc[2][3]);
      acc[3][0] = fmaf(a.w, b.x, acc[3][0]);
      acc[3][1] = fmaf(a.w, b.y, acc[3][1]);
      acc[3][2] = fmaf(a.w, b.z, acc[3][2]);
      acc[3][3] = fmaf(a.w, b.w, acc[3][3]);
    }
    __syncthreads();
  }
#pragma unroll
  for (int i = 0; i < 4; ++i) {
    int row = bm + ty * 4 + i;
    float4 r;
    r.x = acc[i][0] + bias[bn + tx * 4 + 0];
    r.y = acc[i][1] + bias[bn + tx * 4 + 1];
    r.z = acc[i][2] + bias[bn + tx * 4 + 2];
    r.w = acc[i][3] + bias[bn + tx * 4 + 3];
    if (mode == 0) {
      *(float4*)&out[row * 512 + bn + tx * 4] = r;
    } else {
      int bb = row >> 10;
      int tt2 = row & 1023;
      int head = bn >> 6;
      *(float4*)&out[(((bb * NH + head) * TT + tt2) << 6) + tx * 4] = r;
    }
  }
}

__global__ __launch_bounds__(256) void k_gemm(
    const float* __restrict__ A, const float* __restrict__ W,
    const float* __restrict__ bias, float* __restrict__ out, int mode) {
  gemm_body(A, W, bias, out, blockIdx.y * 64, blockIdx.x * 64, mode);
}

__global__ __launch_bounds__(256) void k_gemm_qkv(
    const float* __restrict__ A,
    const float* __restrict__ Wq, const float* __restrict__ bq,
    const float* __restrict__ Wk, const float* __restrict__ bk,
    const float* __restrict__ Wv, const float* __restrict__ bv,
    float* __restrict__ Qf, float* __restrict__ Kf, float* __restrict__ Vf) {
  int which = blockIdx.x >> 3;
  int bn = (blockIdx.x & 7) * 64;
  const float* W = (which == 0) ? Wq : (which == 1) ? Wk : Wv;
  const float* b = (which == 0) ? bq : (which == 1) ? bk : bv;
  float* out = (which == 0) ? Qf : (which == 1) ? Kf : Vf;
  gemm_body(A, W, b, out, blockIdx.y * 64, bn, 1);
}

// ---------------------------------------------------------------------------
// Per-token scalars: fp64 accumulate, store pre-rounded float4 (smooth path
// only — selection never touches these).
// ---------------------------------------------------------------------------
__global__ __launch_bounds__(64) void k_tokscal64(
    const float* __restrict__ Qg, const float* __restrict__ Kg,
    const double* __restrict__ wphid, const float* __restrict__ Wta,
    const float* __restrict__ Wtb, const double* __restrict__ wtaud,
    float4* __restrict__ sqf4, float4* __restrict__ skf4) {
  __shared__ double wp[128], wa[128], wb[128], wt[128];
  int tid = threadIdx.x;
#pragma unroll
  for (int h = 0; h < 2; ++h) {
    int i = h * 64 + tid;
    wp[i] = wphid[i];
    wa[i] = (double)Wta[i];
    wb[i] = (double)Wtb[i];
    wt[i] = wtaud[i];
  }
  __syncthreads();
  int tok = blockIdx.x * 64 + tid;
  const float4* qr = (const float4*)(Qg + (size_t)tok * 64);
  const float4* kr = (const float4*)(Kg + (size_t)tok * 64);
  double sp = 0., sa = 0., sb = 0., st = 0.;
  double kp = 0., ka = 0., kb2 = 0., kt = 0.;
#pragma unroll
  for (int i = 0; i < 16; ++i) {
    float4 qv = qr[i];
    float4 kv = kr[i];
    double q0 = (double)qv.x, q1 = (double)qv.y, q2 = (double)qv.z, q3 = (double)qv.w;
    double k0 = (double)kv.x, k1 = (double)kv.y, k2 = (double)kv.z, k3 = (double)kv.w;
    int d = i * 4;
    sp += q0 * wp[d]; sp += q1 * wp[d + 1]; sp += q2 * wp[d + 2]; sp += q3 * wp[d + 3];
    sa += q0 * wa[d]; sa += q1 * wa[d + 1]; sa += q2 * wa[d + 2]; sa += q3 * wa[d + 3];
    sb += q0 * wb[d]; sb += q1 * wb[d + 1]; sb += q2 * wb[d + 2]; sb += q3 * wb[d + 3];
    st += q0 * wt[d]; st += q1 * wt[d + 1]; st += q2 * wt[d + 2]; st += q3 * wt[d + 3];
    kp += k0 * wp[64 + d]; kp += k1 * wp[64 + d + 1]; kp += k2 * wp[64 + d + 2]; kp += k3 * wp[64 + d + 3];
    ka += k0 * wa[64 + d]; ka += k1 * wa[64 + d + 1]; ka += k2 * wa[64 + d + 2]; ka += k3 * wa[64 + d + 3];
    kb2 += k0 * wb[64 + d]; kb2 += k1 * wb[64 + d + 1]; kb2 += k2 * wb[64 + d + 2]; kb2 += k3 * wb[64 + d + 3];
    kt += k0 * wt[64 + d]; kt += k1 * wt[64 + d + 1]; kt += k2 * wt[64 + d + 2]; kt += k3 * wt[64 + d + 3];
  }
  sqf4[tok] = make_float4((float)sp, (float)sa, (float)sb, (float)st);
  skf4[tok] = make_float4((float)kp, (float)ka, (float)kb2, (float)kt);
}

// ---------------------------------------------------------------------------
// Score GEMM: 128x128 tile, 8x8 register tile, BK=32, fused K-transpose
// staging. d ascending, one fmaf per d per element — bit-identical rounding.
// ---------------------------------------------------------------------------
__global__ __launch_bounds__(256) void k_score(
    const float* __restrict__ Qf, const float* __restrict__ Kf,
    float* __restrict__ Sc) {
  __shared__ float As[32][132];
  __shared__ float Bs[32][132];
  const int bn = blockIdx.x * 128;
  const int bm = blockIdx.y * 128;
  const int bh = blockIdx.z;
  const float* A = Qf + (size_t)bh * (TT * 64);
  const float* K = Kf + (size_t)bh * (TT * 64);
  float* out = Sc + (size_t)bh * (TT * 1024);
  const int tid = threadIdx.x;
  const int tx = tid & 15;
  const int ty = tid >> 4;
  float acc[8][8];
#pragma unroll
  for (int i = 0; i < 8; ++i)
#pragma unroll
    for (int j = 0; j < 8; ++j) acc[i][j] = 0.f;
  for (int k0 = 0; k0 < 64; k0 += 32) {
#pragma unroll
    for (int i = 0; i < 4; ++i) {
      int idx = i * 256 + tid;
      int row = idx >> 3;
      int c4 = (idx & 7) << 2;
      float4 av = *(const float4*)&A[(size_t)(bm + row) * 64 + k0 + c4];
      As[c4 + 0][row] = av.x;
      As[c4 + 1][row] = av.y;
      As[c4 + 2][row] = av.z;
      As[c4 + 3][row] = av.w;
      float4 kv = *(const float4*)&K[(size_t)(bn + row) * 64 + k0 + c4];
      Bs[c4 + 0][row] = kv.x;
      Bs[c4 + 1][row] = kv.y;
      Bs[c4 + 2][row] = kv.z;
      Bs[c4 + 3][row] = kv.w;
    }
    __syncthreads();
#pragma unroll
    for (int kk = 0; kk < 32; ++kk) {
      float4 alo = *(const float4*)&As[kk][ty * 8];
      float4 ahi = *(const float4*)&As[kk][ty * 8 + 4];
      float4 blo = *(const float4*)&Bs[kk][tx * 8];
      float4 bhi = *(const float4*)&Bs[kk][tx * 8 + 4];
      float a[8] = {alo.x, alo.y, alo.z, alo.w, ahi.x, ahi.y, ahi.z, ahi.w};
      float b[8] = {blo.x, blo.y, blo.z, blo.w, bhi.x, bhi.y, bhi.z, bhi.w};
#pragma unroll
      for (int i = 0; i < 8; ++i)
#pragma unroll
        for (int j = 0; j < 8; ++j)
          acc[i][j] = fmaf(a[i], b[j], acc[i][j]);
    }
    __syncthreads();
  }
#pragma unroll
  for (int i = 0; i < 8; ++i) {
    float4 r0 = make_float4(acc[i][0], acc[i][1], acc[i][2], acc[i][3]);
    float4 r1 = make_float4(acc[i][4], acc[i][5], acc[i][6], acc[i][7]);
    size_t base = (size_t)(bm + ty * 8 + i) * 1024 + bn + tx * 8;
    *(float4*)&out[base] = r0;
    *(float4*)&out[base + 4] = r1;
  }
}

// ---------------------------------------------------------------------------
// Top-16 via packed u64 sortable keys: key = (ord(value)<<32) | ~index.
// Unsigned max over keys == (value desc, index asc) — same selection as all
// prior passing rounds, 1 compare per ladder step instead of 3-4.
// One WAVE per query; fp32 smooth path.
// ---------------------------------------------------------------------------
__device__ __forceinline__ unsigned int f2ord(float f) {
  unsigned int u = __float_as_uint(f);
  return ((int)u < 0) ? ~u : (u | 0x80000000u);
}

__global__ __launch_bounds__(256) void k_topk(
    const float* __restrict__ Sc, const float* __restrict__ Vg,
    const float4* __restrict__ sqf4, const float4* __restrict__ skf4,
    const double* __restrict__ ccd, const float* __restrict__ btaP,
    const float* __restrict__ btbP, float* __restrict__ C) {
  const int tid = threadIdx.x;
  const int lane = tid & 63;
  const int wv = tid >> 6;
  const int qg = blockIdx.x * 4 + wv;   // 0..16383
  const int bh = qg >> 10;
  const int qa = qg & 1023;
  const int bb = bh >> 3;
  const int hh = bh & 7;
  const float* rowp = Sc + (size_t)qg * 1024;
  const float* Vbh = Vg + (size_t)bh * (TT * 64);

  // slot s -> key index (s>>2)*256 + lane*4 + (s&3)
  unsigned long long key[16];
#pragma unroll
  for (int j4 = 0; j4 < 4; ++j4) {
    float4 t = *(const float4*)&rowp[j4 * 256 + lane * 4];
    int base = j4 * 256 + lane * 4;
    key[j4 * 4 + 0] = ((unsigned long long)f2ord(t.x) << 32) | (unsigned int)~(base + 0);
    key[j4 * 4 + 1] = ((unsigned long long)f2ord(t.y) << 32) | (unsigned int)~(base + 1);
    key[j4 * 4 + 2] = ((unsigned long long)f2ord(t.z) << 32) | (unsigned int)~(base + 2);
    key[j4 * 4 + 3] = ((unsigned long long)f2ord(t.w) << 32) | (unsigned int)~(base + 3);
  }
  unsigned long long gk[4];
#pragma unroll
  for (int g = 0; g < 4; ++g) {
    gk[g] = key[4 * g];
#pragma unroll
    for (int e = 1; e < 4; ++e)
      if (key[4 * g + e] > gk[g]) gk[g] = key[4 * g + e];
  }
  int myk = 0;  // lane it (<16) holds the it-th selected key index
#pragma unroll 1
  for (int it = 0; it < NTOPK; ++it) {
    unsigned long long bk = gk[0];
    if (gk[1] > bk) bk = gk[1];
    if (gk[2] > bk) bk = gk[2];
    if (gk[3] > bk) bk = gk[3];
#pragma unroll
    for (int off = 32; off >= 1; off >>= 1) {
      unsigned long long ok = __shfl_xor(bk, off, 64);
      if (ok > bk) bk = ok;
    }
    int widx = (int)(~(unsigned int)bk);   // winner's key index, all lanes
    if (lane == it) myk = widx;
    int owner = (widx >> 2) & 63;
    int slot = ((widx >> 8) << 2) | (widx & 3);
    if (lane == owner) {
#pragma unroll
      for (int jj = 0; jj < 16; ++jj)
        if (jj == slot) key[jj] = 0ull;
      int g2 = slot >> 2;
#pragma unroll
      for (int g = 0; g < 4; ++g) {
        if (g == g2) {
          unsigned long long ng = key[4 * g];
#pragma unroll
          for (int e = 1; e < 4; ++e)
            if (key[4 * g + e] > ng) ng = key[4 * g + e];
          gk[g] = ng;
        }
      }
    }
  }
  // fp32 smooth path
  const float cphi = (float)ccd[0];
  const float ctau = (float)ccd[1];
  const float bta0 = btaP[0];
  const float btb0 = btbP[0];
  float4 sq = sqf4[qg];
  float logit = -INFINITY;
  if (lane < 16) {
    float4 sk = skf4[bh * TT + myk];
    float xs = sq.x + sk.x + cphi;
    float ta = sq.y + sk.y + bta0;
    float tb = sq.z + sk.z + btb0;
    float tl = sq.w + sk.w + ctau;
    float phi = 1.f / (1.f + __expf(-xs));
    float ti = 1.f / (1.f + __expf(-(ta + tb)));          // T_SCALAR = 1
    float tau = fmaxf(tl, 0.f) + log1pf(__expf(-fabsf(tl))) + 1e-6f;
    logit = phi / tau * (1.f - __expf(-tau * ti));
  }
  float m = logit;
#pragma unroll
  for (int off = 8; off >= 1; off >>= 1) m = fmaxf(m, __shfl_xor(m, off, 64));
  float e = (lane < 16) ? __expf(logit - m) : 0.f;
  float ssum = e;
#pragma unroll
  for (int off = 8; off >= 1; off >>= 1) ssum += __shfl_xor(ssum, off, 64);
  float w = e / ssum;
  float outv = 0.f;
#pragma unroll
  for (int k2 = 0; k2 < NTOPK; ++k2) {
    float wk = __shfl(w, k2, 64);
    int ik = __shfl(myk, k2, 64);
    outv = fmaf(wk, Vbh[(size_t)ik * 64 + lane], outv);
  }
  C[(bb * TT + qa) * 512 + hh * 64 + lane] = outv;
}

// ---------------------------------------------------------------------------
// Fallback fused attention (round-5 structure) for small workspaces.
// ---------------------------------------------------------------------------
__global__ __launch_bounds__(256) void k_attn(
    const float* __restrict__ Qg, const float* __restrict__ Kg,
    const float* __restrict__ Vg, const float4* __restrict__ sqf4,
    const float4* __restrict__ skf4, const double* __restrict__ ccd,
    const float* __restrict__ btaP, const float* __restrict__ btbP,
    float* __restrict__ C) {
  __shared__ float qs[8][64];
  __shared__ float sc[8][1024];
  const int bh = blockIdx.y;
  const int q0 = blockIdx.x * 8;
  const int tid = threadIdx.x;
  const int lane = tid & 63;
  const int wv = tid >> 6;
  if (tid < 128) {
    int q = tid >> 4, d4 = (tid & 15) << 2;
    *(float4*)&qs[q][d4] = *(const float4*)&Qg[(size_t)(bh * TT + q0 + q) * 64 + d4];
  }
  __syncthreads();
#pragma unroll 1
  for (int c = 0; c < 4; ++c) {
    const int kb = (c * 4 + wv) * 64;
    const float* krow = &Kg[(size_t)(bh * TT + kb + lane) * 64];
    float4 kr[16];
#pragma unroll
    for (int i = 0; i < 16; ++i) kr[i] = *(const float4*)&krow[i * 4];
#pragma unroll
    for (int q = 0; q < 8; ++q) {
      float s = 0.f;
#pragma unroll
      for (int i = 0; i < 16; ++i) {
        float4 q4 = *(const float4*)&qs[q][i * 4];
        s = fmaf(q4.x, kr[i].x, s);
        s = fmaf(q4.y, kr[i].y, s);
        s = fmaf(q4.z, kr[i].z, s);
        s = fmaf(q4.w, kr[i].w, s);
      }
      sc[q][kb + lane] = s;
    }
  }
  __syncthreads();
  const float cphi = (float)ccd[0];
  const float ctau = (float)ccd[1];
  const float bta0 = btaP[0];
  const float btb0 = btbP[0];
  const int bb = bh >> 3;
  const int hh = bh & 7;
  const float* Vbh = Vg + (size_t)bh * (TT * 64);
#pragma unroll 1
  for (int qq = 0; qq < 2; ++qq) {
    const int ql = wv * 2 + qq;
    const int qa = q0 + ql;
    const float* rowp = &sc[ql][0];
    unsigned long long key[16];
#pragma unroll
    for (int jj = 0; jj < 16; ++jj) {
      int idx = jj * 64 + lane;
      key[jj] = ((unsigned long long)f2ord(rowp[idx]) << 32) | (unsigned int)~idx;
    }
    unsigned long long gk[4];
#pragma unroll
    for (int g = 0; g < 4; ++g) {
      gk[g] = key[4 * g];
#pragma unroll
      for (int e = 1; e < 4; ++e)
        if (key[4 * g + e] > gk[g]) gk[g] = key[4 * g + e];
    }
    int myk = 0;
#pragma unroll 1
    for (int it = 0; it < NTOPK; ++it) {
      unsigned long long bk = gk[0];
      if (gk[1] > bk) bk = gk[1];
      if (gk[2] > bk) bk = gk[2];
      if (gk[3] > bk) bk = gk[3];
#pragma unroll
      for (int off = 32; off >= 1; off >>= 1) {
        unsigned long long ok = __shfl_xor(bk, off, 64);
        if (ok > bk) bk = ok;
      }
      int widx = (int)(~(unsigned int)bk);
      if (lane == it) myk = widx;
      int owner = widx & 63;
      int slot = widx >> 6;
      if (lane == owner) {
#pragma unroll
        for (int jj = 0; jj < 16; ++jj)
          if (jj == slot) key[jj] = 0ull;
        int g2 = slot >> 2;
#pragma unroll
        for (int g = 0; g < 4; ++g) {
          if (g == g2) {
            unsigned long long ng = key[4 * g];
#pragma unroll
            for (int e = 1; e < 4; ++e)
              if (key[4 * g + e] > ng) ng = key[4 * g + e];
            gk[g] = ng;
          }
        }
      }
    }
    float4 sq = sqf4[bh * TT + qa];
    float logit = -INFINITY;
    if (lane < 16) {
      float4 sk = skf4[bh * TT + myk];
      float xs = sq.x + sk.x + cphi;
      float ta = sq.y + sk.y + bta0;
      float tb = sq.z + sk.z + btb0;
      float tl = sq.w + sk.w + ctau;
      float phi = 1.f / (1.f + __expf(-xs));
      float ti = 1.f / (1.f + __expf(-(ta + tb)));
      float tau = fmaxf(tl, 0.f) + log1pf(__expf(-fabsf(tl))) + 1e-6f;
      logit = phi / tau * (1.f - __expf(-tau * ti));
    }
    float m = logit;
#pragma unroll
    for (int off = 8; off >= 1; off >>= 1) m = fmaxf(m, __shfl_xor(m, off, 64));
    float e = (lane < 16) ? __expf(logit - m) : 0.f;
    float ssum = e;
#pragma unroll
    for (int off = 8; off >= 1; off >>= 1) ssum += __shfl_xor(ssum, off, 64);
    float w = e / ssum;
    float outv = 0.f;
#pragma unroll
    for (int k2 = 0; k2 < NTOPK; ++k2) {
      float wk = __shfl(w, k2, 64);
      int ik = __shfl(myk, k2, 64);
      outv = fmaf(wk, Vbh[(size_t)ik * 64 + lane], outv);
    }
    C[(bb * TT + qa) * 512 + hh * 64 + lane] = outv;
  }
}

// ---------------------------------------------------------------------------
extern "C" void kernel_launch(void* const* d_in, const int* in_sizes, int n_in,
                              void* d_out, int out_size, void* d_ws, size_t ws_size,
                              hipStream_t stream) {
  (void)in_sizes; (void)n_in; (void)out_size;
  const float* x   = (const float*)d_in[0];
  const float* Wq  = (const float*)d_in[1];
  const float* bq  = (const float*)d_in[2];
  const float* Wk  = (const float*)d_in[3];
  const float* bk  = (const float*)d_in[4];
  const float* Wv  = (const float*)d_in[5];
  const float* bv  = (const float*)d_in[6];
  const float* Wo  = (const float*)d_in[7];
  const float* bo  = (const float*)d_in[8];
  const float* Wpi = (const float*)d_in[9];
  const float* bpi = (const float*)d_in[10];
  const float* Wpo = (const float*)d_in[11];
  const float* bpo = (const float*)d_in[12];
  const float* Wta = (const float*)d_in[13];
  const float* bta = (const float*)d_in[14];
  const float* Wtb = (const float*)d_in[15];
  const float* btb = (const float*)d_in[16];
  const float* Wti = (const float*)d_in[17];
  const float* bti = (const float*)d_in[18];
  const float* Wto = (const float*)d_in[19];
  const float* bto = (const float*)d_in[20];

  float* fs = (float*)d_ws;
  float4* sqf4 = (float4*)fs;                 // 65536 floats
  float4* skf4 = (float4*)(fs + 65536);       // 65536 floats
  double* wphid = (double*)(fs + 131072);     // 128 doubles (8B-aligned: 512KB off)
  double* wtaud = (double*)(fs + 131328);     // 128 doubles
  double* ccd   = (double*)(fs + 131584);     // 2 doubles
  float* Qf = fs + 132096;
  float* Kf = Qf + 1048576;
  float* Vf = Kf + 1048576;
  float* Cf = Vf + 1048576;
  float* Sc = Cf + 1048576;                   // 16,777,216 floats (64 MB)
  const size_t need = (size_t)(132096 + 4 * 1048576 + 16777216) * 4;

  hipLaunchKernelGGL(k_collapse64, dim3(17), dim3(256), 0, stream,
                     Wpi, bpi, Wpo, bpo, Wti, bti, Wto, bto, wphid, wtaud, ccd);
  hipLaunchKernelGGL(k_gemm_qkv, dim3(24, 32), dim3(256), 0, stream,
                     x, Wq, bq, Wk, bk, Wv, bv, Qf, Kf, Vf);
  hipLaunchKernelGGL(k_tokscal64, dim3(NTOK / 64), dim3(64), 0, stream,
                     Qf, Kf, wphid, Wta, Wtb, wtaud, sqf4, skf4);
  if (ws_size >= need) {
    hipLaunchKernelGGL(k_score, dim3(8, 8, 16), dim3(256), 0, stream, Qf, Kf, Sc);
    hipLaunchKernelGGL(k_topk, dim3(NTOK / 4), dim3(256), 0, stream,
                       Sc, Vf, sqf4, skf4, ccd, bta, btb, Cf);
  } else {
    hipLaunchKernelGGL(k_attn, dim3(TT / 8, NBH), dim3(256), 0, stream,
                       Qf, Kf, Vf, sqf4, skf4, ccd, bta, btb, Cf);
  }
  hipLaunchKernelGGL(k_gemm, dim3(8, 32), dim3(256), 0, stream,
                     Cf, Wo, bo, (float*)d_out, 0);
}